// Round 4
// baseline (776.487 us; speedup 1.0000x reference)
//
#include <hip/hip_runtime.h>

#define B_  2
#define H_  16
#define S_  2048
#define D_  64
#define BH_ (B_*H_)
#define QT  64
#define KT  64
#define NKT (S_/KT)
#define LDQ 72   // padded LDS row stride (elements); 144 B keeps 16B alignment

typedef __attribute__((ext_vector_type(8))) short bf16x8;
typedef __attribute__((ext_vector_type(4))) float f32x4;

static __device__ __forceinline__ ushort f2bf(float f) {
  union { float f; unsigned u; } v; v.f = f;
  unsigned r = (v.u + 0x7fff + ((v.u >> 16) & 1)) >> 16;  // RNE
  return (ushort)r;
}

// Compute one wave's 16q x 64k score tile from sQ-fragments (pre-scaled by 1/8)
// and the staged K tile. acc[t]: tile t covers keys t*16 + (lane&15);
// rows (queries) = (lane>>4)*4 + j.
static __device__ __forceinline__ void score_tiles(
    f32x4 acc[4], const ushort* __restrict__ sK, const bf16x8 qa[2],
    int l15, int lq, const int* __restrict__ mg, int kbase)
{
#pragma unroll
  for (int t = 0; t < 4; ++t) {
    const bf16x8 kb0 = *(const bf16x8*)&sK[(t*16 + l15)*LDQ +      lq*8];
    const bf16x8 kb1 = *(const bf16x8*)&sK[(t*16 + l15)*LDQ + 32 + lq*8];
    f32x4 a = {0.f, 0.f, 0.f, 0.f};
    a = __builtin_amdgcn_mfma_f32_16x16x32_bf16(qa[0], kb0, a, 0, 0, 0);
    a = __builtin_amdgcn_mfma_f32_16x16x32_bf16(qa[1], kb1, a, 0, 0, 0);
    const int mv = mg[kbase + t*16 + l15];
    if (mv == 0) { a[0] = -1e30f; a[1] = -1e30f; a[2] = -1e30f; a[3] = -1e30f; }
    acc[t] = a;
  }
}

__global__ __launch_bounds__(256)
void attn_kernel(const float* __restrict__ Q, const float* __restrict__ K,
                 const float* __restrict__ V, const int* __restrict__ mask,
                 float* __restrict__ outO, float* __restrict__ outP)
{
  __shared__ ushort sQ[QT * LDQ];
  __shared__ ushort sK[KT * LDQ];
  __shared__ ushort sVt[D_ * LDQ];           // sVt[d][key]
  __shared__ ushort sP[4][16 * LDQ];         // per-wave P tile [16q][64k]

  const int tid  = threadIdx.x;
  const int wave = tid >> 6;
  const int lane = tid & 63;
  const int l15  = lane & 15;
  const int lq   = lane >> 4;

  const int qt = blockIdx.x;   // query tile 0..31
  const int bh = blockIdx.y;   // 0..31
  const int b  = bh >> 4;      // H_=16
  const int q0 = qt * QT;

  const float* Qg = Q + (size_t)(bh*S_ + q0) * D_;
  const float* Kg = K + (size_t)bh * S_ * D_;
  const float* Vg = V + (size_t)bh * S_ * D_;
  const int*   mg = mask + b * S_;
  float* Og = outO + (size_t)(bh*S_ + q0) * D_;
  float* Pg = outP + ((size_t)(bh*S_ + q0)) * S_;

  const int srow = tid >> 2;          // 0..63
  const int sd0  = (tid & 3) * 16;    // 0,16,32,48

  // ---- stage Q (scaled by 1/8) ----
  {
    const float* src = Qg + (size_t)srow * D_ + sd0;
    ushort* dst = &sQ[srow*LDQ + sd0];
#pragma unroll
    for (int i = 0; i < 16; i += 4) {
      float4 v = *(const float4*)(src + i);
      dst[i+0] = f2bf(v.x * 0.125f);
      dst[i+1] = f2bf(v.y * 0.125f);
      dst[i+2] = f2bf(v.z * 0.125f);
      dst[i+3] = f2bf(v.w * 0.125f);
    }
  }
  __syncthreads();

  // Q fragments, held in registers for the whole kernel
  bf16x8 qa[2];
#pragma unroll
  for (int c = 0; c < 2; ++c)
    qa[c] = *(const bf16x8*)&sQ[(wave*16 + l15)*LDQ + c*32 + lq*8];

  // per-lane row stats for queries (lq*4 + j) of this wave's 16
  float m_r[4] = {-1e30f, -1e30f, -1e30f, -1e30f};
  float l_r[4] = {0.f, 0.f, 0.f, 0.f};

  // ================= PASS 1: row max & sum =================
  for (int kt = 0; kt < NKT; ++kt) {
    __syncthreads();   // previous tile's readers done
    {
      const float* src = Kg + (size_t)(kt*KT + srow) * D_ + sd0;
      ushort* dst = &sK[srow*LDQ + sd0];
#pragma unroll
      for (int i = 0; i < 16; i += 4) {
        float4 v = *(const float4*)(src + i);
        dst[i+0] = f2bf(v.x); dst[i+1] = f2bf(v.y);
        dst[i+2] = f2bf(v.z); dst[i+3] = f2bf(v.w);
      }
    }
    __syncthreads();

    f32x4 acc[4];
    score_tiles(acc, sK, qa, l15, lq, mg, kt*KT);

#pragma unroll
    for (int j = 0; j < 4; ++j) {
      float v = fmaxf(fmaxf(acc[0][j], acc[1][j]), fmaxf(acc[2][j], acc[3][j]));
#pragma unroll
      for (int s = 1; s < 16; s <<= 1) v = fmaxf(v, __shfl_xor(v, s));
      const float mn = fmaxf(m_r[j], v);
      float ps = __expf(acc[0][j] - mn) + __expf(acc[1][j] - mn)
               + __expf(acc[2][j] - mn) + __expf(acc[3][j] - mn);
#pragma unroll
      for (int s = 1; s < 16; s <<= 1) ps += __shfl_xor(ps, s);
      l_r[j] = l_r[j] * __expf(m_r[j] - mn) + ps;
      m_r[j] = mn;
    }
  }

  float inv_l[4];
#pragma unroll
  for (int j = 0; j < 4; ++j) inv_l[j] = 1.0f / l_r[j];

  // O accumulators: nsub 0..3 -> d = nsub*16 + l15; row = lq*4 + j
  f32x4 oacc[4];
#pragma unroll
  for (int n = 0; n < 4; ++n) { oacc[n][0]=0.f; oacc[n][1]=0.f; oacc[n][2]=0.f; oacc[n][3]=0.f; }

  ushort* sPw = &sP[wave][0];

  // ================= PASS 2: probs + PV =================
  for (int kt = 0; kt < NKT; ++kt) {
    __syncthreads();   // previous tile's sK/sVt readers done
    {
      const float* src = Kg + (size_t)(kt*KT + srow) * D_ + sd0;
      ushort* dst = &sK[srow*LDQ + sd0];
#pragma unroll
      for (int i = 0; i < 16; i += 4) {
        float4 v = *(const float4*)(src + i);
        dst[i+0] = f2bf(v.x); dst[i+1] = f2bf(v.y);
        dst[i+2] = f2bf(v.z); dst[i+3] = f2bf(v.w);
      }
    }
    {
      const int vkey = tid & 63;
      const int vd0  = (tid >> 6) * 16;
      const float* vsrc = Vg + (size_t)(kt*KT + vkey) * D_ + vd0;
#pragma unroll
      for (int i = 0; i < 16; i += 4) {
        float4 v = *(const float4*)(vsrc + i);
        sVt[(vd0+i+0)*LDQ + vkey] = f2bf(v.x);
        sVt[(vd0+i+1)*LDQ + vkey] = f2bf(v.y);
        sVt[(vd0+i+2)*LDQ + vkey] = f2bf(v.z);
        sVt[(vd0+i+3)*LDQ + vkey] = f2bf(v.w);
      }
    }
    __syncthreads();

    f32x4 acc[4];
    score_tiles(acc, sK, qa, l15, lq, mg, kt*KT);

    // p = exp(s - m) / l  -> stage to LDS (bf16)
#pragma unroll
    for (int t = 0; t < 4; ++t) {
#pragma unroll
      for (int j = 0; j < 4; ++j) {
        const float p = __expf(acc[t][j] - m_r[j]) * inv_l[j];
        sPw[(lq*4 + j)*LDQ + t*16 + l15] = f2bf(p);
      }
    }
    __syncthreads();   // sP visible (also orders sVt reads vs next staging)

    // write probs: per i, 4 rows x 256B fully-contiguous segments
#pragma unroll
    for (int i = 0; i < 4; ++i) {
      const int r = lq + i*4;           // 0..15
      const ushort* ps = &sPw[r*LDQ + l15*4];
      float4 o;
      o.x = __uint_as_float((unsigned)ps[0] << 16);
      o.y = __uint_as_float((unsigned)ps[1] << 16);
      o.z = __uint_as_float((unsigned)ps[2] << 16);
      o.w = __uint_as_float((unsigned)ps[3] << 16);
      *(float4*)&Pg[(size_t)(wave*16 + r)*S_ + kt*KT + l15*4] = o;
    }

    // PV: O[16q x 64d] += P[16q x 64k] * V[64k x 64d]
#pragma unroll
    for (int c = 0; c < 2; ++c) {
      const bf16x8 pa = *(const bf16x8*)&sPw[l15*LDQ + c*32 + lq*8];
#pragma unroll
      for (int n = 0; n < 4; ++n) {
        const bf16x8 vb = *(const bf16x8*)&sVt[(n*16 + l15)*LDQ + c*32 + lq*8];
        oacc[n] = __builtin_amdgcn_mfma_f32_16x16x32_bf16(pa, vb, oacc[n], 0, 0, 0);
      }
    }
  }

  // ---- write O ----
#pragma unroll
  for (int n = 0; n < 4; ++n) {
#pragma unroll
    for (int j = 0; j < 4; ++j) {
      Og[(size_t)(wave*16 + lq*4 + j)*D_ + n*16 + l15] = oacc[n][j];
    }
  }
}

extern "C" void kernel_launch(void* const* d_in, const int* in_sizes, int n_in,
                              void* d_out, int out_size, void* d_ws, size_t ws_size,
                              hipStream_t stream) {
  const float* Q = (const float*)d_in[0];
  const float* K = (const float*)d_in[1];
  const float* V = (const float*)d_in[2];
  const int* mask = (const int*)d_in[3];
  float* outO = (float*)d_out;
  float* outP = outO + (size_t)B_ * H_ * S_ * D_;
  dim3 grid(S_ / QT, BH_);
  attn_kernel<<<grid, dim3(256), 0, stream>>>(Q, K, V, mask, outO, outP);
}

// Round 5
// 707.234 us; speedup vs baseline: 1.0979x; 1.0979x over previous
//
#include <hip/hip_runtime.h>

#define B_  2
#define H_  16
#define S_  2048
#define D_  64
#define BH_ (B_*H_)
#define NKT (S_/64)
#define LDQ 72   // padded LDS row stride for fallback + sP (elements)
#define LDP 72

typedef __attribute__((ext_vector_type(8))) short bf16x8;
typedef __attribute__((ext_vector_type(4))) float f32x4;
typedef __attribute__((address_space(1))) const char gchar;
typedef __attribute__((address_space(3))) char lchar;

#define QK_SCALE 0.18033688011112042f   // (1/8) * log2(e)

static __device__ __forceinline__ ushort f2bf(float f) {
  union { float f; unsigned u; } v; v.f = f;
  unsigned r = (v.u + 0x7fff + ((v.u >> 16) & 1)) >> 16;  // RNE
  return (ushort)r;
}

static __device__ __forceinline__ uint4 pack8(const float* e, float sc) {
  uint4 p;
  p.x = (unsigned)f2bf(e[0]*sc) | ((unsigned)f2bf(e[1]*sc) << 16);
  p.y = (unsigned)f2bf(e[2]*sc) | ((unsigned)f2bf(e[3]*sc) << 16);
  p.z = (unsigned)f2bf(e[4]*sc) | ((unsigned)f2bf(e[5]*sc) << 16);
  p.w = (unsigned)f2bf(e[6]*sc) | ((unsigned)f2bf(e[7]*sc) << 16);
  return p;
}

// ============ kernel0: convert fp32 -> bf16, tile-order, XOR-granule-swizzled ============
// mode 0: Q (scaled by QK_SCALE), mode 1: K, mode 2: V transposed (Vt[d][key]).
// Element (r,c) of a 64x64 tile -> byte  r*128 + (((c>>3) ^ (r&7))<<4) + (c&7)*2.
__global__ __launch_bounds__(256)
void conv_kernel(const float* __restrict__ Q, const float* __restrict__ K,
                 const float* __restrict__ V,
                 ushort* __restrict__ Qw, ushort* __restrict__ Kw, ushort* __restrict__ Vw)
{
  const int tile = blockIdx.x, bh = blockIdx.y, mode = blockIdx.z;
  const int tid = threadIdx.x;
  const float* src = (mode == 0 ? Q : (mode == 1 ? K : V)) + ((size_t)bh*S_ + tile*64) * D_;
  ushort* dst = (mode == 0 ? Qw : (mode == 1 ? Kw : Vw)) + ((size_t)bh*NKT + tile) * 4096;

  const int r  = tid >> 2;          // 0..63
  const int c0 = (tid & 3) * 16;    // 0,16,32,48

  if (mode < 2) {
    const float sc = (mode == 0) ? QK_SCALE : 1.0f;
    const float4* s4 = (const float4*)(src + (size_t)r*D_ + c0);
    float e[16];
#pragma unroll
    for (int i = 0; i < 4; ++i) {
      float4 v = s4[i];
      e[i*4+0] = v.x; e[i*4+1] = v.y; e[i*4+2] = v.z; e[i*4+3] = v.w;
    }
#pragma unroll
    for (int g = 0; g < 2; ++g) {
      const int gi = ((c0 >> 3) + g) ^ (r & 7);
      *(uint4*)((char*)dst + r*128 + gi*16) = pack8(e + g*8, sc);
    }
  } else {
    __shared__ float t[64][65];
    const float4* s4 = (const float4*)(src + (size_t)r*D_ + c0);
#pragma unroll
    for (int i = 0; i < 4; ++i) {
      float4 v = s4[i];
      t[r][c0 + i*4 + 0] = v.x; t[r][c0 + i*4 + 1] = v.y;
      t[r][c0 + i*4 + 2] = v.z; t[r][c0 + i*4 + 3] = v.w;
    }
    __syncthreads();
    // this thread emits Vt row d=r, keys c0..c0+15
    float e[16];
#pragma unroll
    for (int i = 0; i < 16; ++i) e[i] = t[c0 + i][r];
#pragma unroll
    for (int g = 0; g < 2; ++g) {
      const int gi = ((c0 >> 3) + g) ^ (r & 7);
      *(uint4*)((char*)dst + r*128 + gi*16) = pack8(e + g*8, 1.0f);
    }
  }
}

// ============ async stage: one 8KB tile (64x64 bf16) global -> LDS, linear ============
static __device__ __forceinline__ void stage8k(void* lds, const void* src, int wave, int lane) {
  const char* s = (const char*)src + lane*16;
  char* d = (char*)lds;
#pragma unroll
  for (int i = 0; i < 2; ++i) {
    const int off = (wave + i*4) << 10;   // wave chunks: w and w+4 (1KB each)
    __builtin_amdgcn_global_load_lds((gchar*)(s + off), (lchar*)(d + off), 16, 0, 0);
  }
}

// ============ main attention kernel (pre-converted operands) ============
__global__ __launch_bounds__(256, 3)
void attn2_kernel(const ushort* __restrict__ Qw, const ushort* __restrict__ Kw,
                  const ushort* __restrict__ Vw, const int* __restrict__ mask,
                  float* __restrict__ outO, float* __restrict__ outP)
{
  __shared__ ushort sQ[4096];
  __shared__ ushort sK[2][4096];
  __shared__ ushort sVt[2][4096];
  __shared__ ushort sP[4][16 * LDP];

  const int tid  = threadIdx.x;
  const int wave = tid >> 6;
  const int lane = tid & 63;
  const int l15  = lane & 15;
  const int lq   = lane >> 4;
  const int rxor = l15 & 7;            // row&7 for any row = X*16 + l15

  const int qt = blockIdx.x;           // 0..31
  const int bh = blockIdx.y;           // 0..31
  const int b  = bh >> 4;

  const ushort* Qt = Qw + ((size_t)bh*NKT + qt) * 4096;
  const ushort* Kt = Kw + (size_t)bh*NKT * 4096;
  const ushort* Vt = Vw + (size_t)bh*NKT * 4096;
  const int*    mg = mask + b * S_;
  float* Og = outO + (size_t)(bh*S_ + qt*64) * D_;
  float* Pg = outP + (size_t)(bh*S_ + qt*64) * S_;

  stage8k(sQ, Qt, wave, lane);
  stage8k(sK[0], Kt, wave, lane);
  __syncthreads();

  bf16x8 qa[2];
#pragma unroll
  for (int c = 0; c < 2; ++c)
    qa[c] = *(const bf16x8*)((const char*)sQ + (wave*16 + l15)*128 + (((c*4 + lq) ^ rxor) << 4));

  float m_r[4] = {-1e30f, -1e30f, -1e30f, -1e30f};
  float l_r[4] = {0.f, 0.f, 0.f, 0.f};

  // ---------- PASS 1: per-lane online (m,l), no per-tile shuffles ----------
  int cur = 0;
  for (int kt = 0; kt < NKT; ++kt) {
    if (kt + 1 < NKT) stage8k(sK[cur ^ 1], Kt + (size_t)(kt + 1)*4096, wave, lane);
    int mv[4];
#pragma unroll
    for (int t = 0; t < 4; ++t) mv[t] = mg[kt*64 + t*16 + l15];
    f32x4 acc[4];
#pragma unroll
    for (int t = 0; t < 4; ++t) {
      const char* rowp = (const char*)sK[cur] + (t*16 + l15)*128;
      const bf16x8 kb0 = *(const bf16x8*)(rowp + (((0 + lq) ^ rxor) << 4));
      const bf16x8 kb1 = *(const bf16x8*)(rowp + (((4 + lq) ^ rxor) << 4));
      f32x4 a = {0.f, 0.f, 0.f, 0.f};
      a = __builtin_amdgcn_mfma_f32_16x16x32_bf16(qa[0], kb0, a, 0, 0, 0);
      a = __builtin_amdgcn_mfma_f32_16x16x32_bf16(qa[1], kb1, a, 0, 0, 0);
      if (mv[t] == 0) { a[0] = -1e30f; a[1] = -1e30f; a[2] = -1e30f; a[3] = -1e30f; }
      acc[t] = a;
    }
#pragma unroll
    for (int j = 0; j < 4; ++j) {
      const float vmax = fmaxf(fmaxf(acc[0][j], acc[1][j]), fmaxf(acc[2][j], acc[3][j]));
      const float mn = fmaxf(m_r[j], vmax);
      const float ps = __builtin_amdgcn_exp2f(acc[0][j] - mn) + __builtin_amdgcn_exp2f(acc[1][j] - mn)
                     + __builtin_amdgcn_exp2f(acc[2][j] - mn) + __builtin_amdgcn_exp2f(acc[3][j] - mn);
      l_r[j] = l_r[j] * __builtin_amdgcn_exp2f(m_r[j] - mn) + ps;
      m_r[j] = mn;
    }
    __syncthreads();
    cur ^= 1;
  }

  // merge the 16 per-lane states per row; madj = M + log2(l) folds the 1/l divide
  float madj[4];
#pragma unroll
  for (int j = 0; j < 4; ++j) {
    float m = m_r[j], l = l_r[j];
#pragma unroll
    for (int s = 1; s < 16; s <<= 1) {
      const float om = __shfl_xor(m, s);
      const float ol = __shfl_xor(l, s);
      const float mn = fmaxf(m, om);
      l = l * __builtin_amdgcn_exp2f(m - mn) + ol * __builtin_amdgcn_exp2f(om - mn);
      m = mn;
    }
    madj[j] = m + __builtin_amdgcn_logf(l);
  }

  f32x4 oacc[4];
#pragma unroll
  for (int n = 0; n < 4; ++n) { oacc[n][0]=0.f; oacc[n][1]=0.f; oacc[n][2]=0.f; oacc[n][3]=0.f; }
  ushort* sPw = &sP[wave][0];

  // ---------- PASS 2: probs + PV ----------
  stage8k(sK[0], Kt, wave, lane);
  stage8k(sVt[0], Vt, wave, lane);
  cur = 0;
  __syncthreads();

  for (int kt = 0; kt < NKT; ++kt) {
    if (kt + 1 < NKT) {
      stage8k(sK[cur ^ 1], Kt + (size_t)(kt + 1)*4096, wave, lane);
      stage8k(sVt[cur ^ 1], Vt + (size_t)(kt + 1)*4096, wave, lane);
    }
    int mv[4];
#pragma unroll
    for (int t = 0; t < 4; ++t) mv[t] = mg[kt*64 + t*16 + l15];
    f32x4 acc[4];
#pragma unroll
    for (int t = 0; t < 4; ++t) {
      const char* rowp = (const char*)sK[cur] + (t*16 + l15)*128;
      const bf16x8 kb0 = *(const bf16x8*)(rowp + (((0 + lq) ^ rxor) << 4));
      const bf16x8 kb1 = *(const bf16x8*)(rowp + (((4 + lq) ^ rxor) << 4));
      f32x4 a = {0.f, 0.f, 0.f, 0.f};
      a = __builtin_amdgcn_mfma_f32_16x16x32_bf16(qa[0], kb0, a, 0, 0, 0);
      a = __builtin_amdgcn_mfma_f32_16x16x32_bf16(qa[1], kb1, a, 0, 0, 0);
      if (mv[t] == 0) { a[0] = -1e30f; a[1] = -1e30f; a[2] = -1e30f; a[3] = -1e30f; }
      acc[t] = a;
    }
    // P = 2^(s - madj), bf16, wave-private LDS (no barrier needed)
#pragma unroll
    for (int t = 0; t < 4; ++t) {
#pragma unroll
      for (int j = 0; j < 4; ++j) {
        sPw[(lq*4 + j)*LDP + t*16 + l15] = f2bf(__builtin_amdgcn_exp2f(acc[t][j] - madj[j]));
      }
    }
    // probs write: 4 rows x 256B contiguous segments per instruction
#pragma unroll
    for (int i = 0; i < 4; ++i) {
      const int r = lq + i*4;
      const ushort* ps = &sPw[r*LDP + l15*4];
      float4 o;
      o.x = __uint_as_float((unsigned)ps[0] << 16);
      o.y = __uint_as_float((unsigned)ps[1] << 16);
      o.z = __uint_as_float((unsigned)ps[2] << 16);
      o.w = __uint_as_float((unsigned)ps[3] << 16);
      *(float4*)&Pg[(size_t)(wave*16 + r)*S_ + kt*64 + l15*4] = o;
    }
    // PV
#pragma unroll
    for (int c2 = 0; c2 < 2; ++c2) {
      const bf16x8 pa = *(const bf16x8*)((const char*)sPw + l15*(LDP*2) + c2*64 + lq*16);
#pragma unroll
      for (int n = 0; n < 4; ++n) {
        const bf16x8 vb = *(const bf16x8*)((const char*)sVt[cur] + (n*16 + l15)*128 + (((c2*4 + lq) ^ rxor) << 4));
        oacc[n] = __builtin_amdgcn_mfma_f32_16x16x32_bf16(pa, vb, oacc[n], 0, 0, 0);
      }
    }
    __syncthreads();
    cur ^= 1;
  }

#pragma unroll
  for (int n = 0; n < 4; ++n)
#pragma unroll
    for (int j = 0; j < 4; ++j)
      Og[(size_t)(wave*16 + lq*4 + j)*D_ + n*16 + l15] = oacc[n][j];
}

// ============ fallback: proven round-4 kernel (used only if ws too small) ============
static __device__ __forceinline__ void score_tiles_fb(
    f32x4 acc[4], const ushort* __restrict__ sK, const bf16x8 qa[2],
    int l15, int lq, const int* __restrict__ mg, int kbase)
{
#pragma unroll
  for (int t = 0; t < 4; ++t) {
    const bf16x8 kb0 = *(const bf16x8*)&sK[(t*16 + l15)*LDQ +      lq*8];
    const bf16x8 kb1 = *(const bf16x8*)&sK[(t*16 + l15)*LDQ + 32 + lq*8];
    f32x4 a = {0.f, 0.f, 0.f, 0.f};
    a = __builtin_amdgcn_mfma_f32_16x16x32_bf16(qa[0], kb0, a, 0, 0, 0);
    a = __builtin_amdgcn_mfma_f32_16x16x32_bf16(qa[1], kb1, a, 0, 0, 0);
    const int mv = mg[kbase + t*16 + l15];
    if (mv == 0) { a[0] = -1e30f; a[1] = -1e30f; a[2] = -1e30f; a[3] = -1e30f; }
    acc[t] = a;
  }
}

__global__ __launch_bounds__(256)
void attn_kernel(const float* __restrict__ Q, const float* __restrict__ K,
                 const float* __restrict__ V, const int* __restrict__ mask,
                 float* __restrict__ outO, float* __restrict__ outP)
{
  __shared__ ushort sQ[64 * LDQ];
  __shared__ ushort sK[64 * LDQ];
  __shared__ ushort sVt[D_ * LDQ];
  __shared__ ushort sP[4][16 * LDQ];

  const int tid  = threadIdx.x;
  const int wave = tid >> 6;
  const int lane = tid & 63;
  const int l15  = lane & 15;
  const int lq   = lane >> 4;
  const int qt = blockIdx.x;
  const int bh = blockIdx.y;
  const int b  = bh >> 4;
  const int q0 = qt * 64;

  const float* Qg = Q + (size_t)(bh*S_ + q0) * D_;
  const float* Kg = K + (size_t)bh * S_ * D_;
  const float* Vg = V + (size_t)bh * S_ * D_;
  const int*   mg = mask + b * S_;
  float* Og = outO + (size_t)(bh*S_ + q0) * D_;
  float* Pg = outP + ((size_t)(bh*S_ + q0)) * S_;

  const int srow = tid >> 2;
  const int sd0  = (tid & 3) * 16;

  {
    const float* src = Qg + (size_t)srow * D_ + sd0;
    ushort* dst = &sQ[srow*LDQ + sd0];
#pragma unroll
    for (int i = 0; i < 16; i += 4) {
      float4 v = *(const float4*)(src + i);
      dst[i+0] = f2bf(v.x * 0.125f); dst[i+1] = f2bf(v.y * 0.125f);
      dst[i+2] = f2bf(v.z * 0.125f); dst[i+3] = f2bf(v.w * 0.125f);
    }
  }
  __syncthreads();

  bf16x8 qa[2];
#pragma unroll
  for (int c = 0; c < 2; ++c)
    qa[c] = *(const bf16x8*)&sQ[(wave*16 + l15)*LDQ + c*32 + lq*8];

  float m_r[4] = {-1e30f, -1e30f, -1e30f, -1e30f};
  float l_r[4] = {0.f, 0.f, 0.f, 0.f};

  for (int kt = 0; kt < NKT; ++kt) {
    __syncthreads();
    {
      const float* src = Kg + (size_t)(kt*64 + srow) * D_ + sd0;
      ushort* dst = &sK[srow*LDQ + sd0];
#pragma unroll
      for (int i = 0; i < 16; i += 4) {
        float4 v = *(const float4*)(src + i);
        dst[i+0] = f2bf(v.x); dst[i+1] = f2bf(v.y);
        dst[i+2] = f2bf(v.z); dst[i+3] = f2bf(v.w);
      }
    }
    __syncthreads();
    f32x4 acc[4];
    score_tiles_fb(acc, sK, qa, l15, lq, mg, kt*64);
#pragma unroll
    for (int j = 0; j < 4; ++j) {
      float v = fmaxf(fmaxf(acc[0][j], acc[1][j]), fmaxf(acc[2][j], acc[3][j]));
#pragma unroll
      for (int s = 1; s < 16; s <<= 1) v = fmaxf(v, __shfl_xor(v, s));
      const float mn = fmaxf(m_r[j], v);
      float ps = __expf(acc[0][j] - mn) + __expf(acc[1][j] - mn)
               + __expf(acc[2][j] - mn) + __expf(acc[3][j] - mn);
#pragma unroll
      for (int s = 1; s < 16; s <<= 1) ps += __shfl_xor(ps, s);
      l_r[j] = l_r[j] * __expf(m_r[j] - mn) + ps;
      m_r[j] = mn;
    }
  }

  float inv_l[4];
#pragma unroll
  for (int j = 0; j < 4; ++j) inv_l[j] = 1.0f / l_r[j];

  f32x4 oacc[4];
#pragma unroll
  for (int n = 0; n < 4; ++n) { oacc[n][0]=0.f; oacc[n][1]=0.f; oacc[n][2]=0.f; oacc[n][3]=0.f; }
  ushort* sPw = &sP[wave][0];

  for (int kt = 0; kt < NKT; ++kt) {
    __syncthreads();
    {
      const float* src = Kg + (size_t)(kt*64 + srow) * D_ + sd0;
      ushort* dst = &sK[srow*LDQ + sd0];
#pragma unroll
      for (int i = 0; i < 16; i += 4) {
        float4 v = *(const float4*)(src + i);
        dst[i+0] = f2bf(v.x); dst[i+1] = f2bf(v.y);
        dst[i+2] = f2bf(v.z); dst[i+3] = f2bf(v.w);
      }
    }
    {
      const int vkey = tid & 63;
      const int vd0  = (tid >> 6) * 16;
      const float* vsrc = Vg + (size_t)(kt*64 + vkey) * D_ + vd0;
#pragma unroll
      for (int i = 0; i < 16; i += 4) {
        float4 v = *(const float4*)(vsrc + i);
        sVt[(vd0+i+0)*LDQ + vkey] = f2bf(v.x);
        sVt[(vd0+i+1)*LDQ + vkey] = f2bf(v.y);
        sVt[(vd0+i+2)*LDQ + vkey] = f2bf(v.z);
        sVt[(vd0+i+3)*LDQ + vkey] = f2bf(v.w);
      }
    }
    __syncthreads();
    f32x4 acc[4];
    score_tiles_fb(acc, sK, qa, l15, lq, mg, kt*64);
#pragma unroll
    for (int t = 0; t < 4; ++t)
#pragma unroll
      for (int j = 0; j < 4; ++j) {
        const float p = __expf(acc[t][j] - m_r[j]) * inv_l[j];
        sPw[(lq*4 + j)*LDQ + t*16 + l15] = f2bf(p);
      }
    __syncthreads();
#pragma unroll
    for (int i = 0; i < 4; ++i) {
      const int r = lq + i*4;
      const ushort* ps = &sPw[r*LDQ + l15*4];
      float4 o;
      o.x = __uint_as_float((unsigned)ps[0] << 16);
      o.y = __uint_as_float((unsigned)ps[1] << 16);
      o.z = __uint_as_float((unsigned)ps[2] << 16);
      o.w = __uint_as_float((unsigned)ps[3] << 16);
      *(float4*)&Pg[(size_t)(wave*16 + r)*S_ + kt*64 + l15*4] = o;
    }
#pragma unroll
    for (int c = 0; c < 2; ++c) {
      const bf16x8 pa = *(const bf16x8*)&sPw[l15*LDQ + c*32 + lq*8];
#pragma unroll
      for (int n = 0; n < 4; ++n) {
        const bf16x8 vb = *(const bf16x8*)&sVt[(n*16 + l15)*LDQ + c*32 + lq*8];
        oacc[n] = __builtin_amdgcn_mfma_f32_16x16x32_bf16(pa, vb, oacc[n], 0, 0, 0);
      }
    }
  }
#pragma unroll
  for (int n = 0; n < 4; ++n)
#pragma unroll
    for (int j = 0; j < 4; ++j)
      Og[(size_t)(wave*16 + lq*4 + j)*D_ + n*16 + l15] = oacc[n][j];
}

extern "C" void kernel_launch(void* const* d_in, const int* in_sizes, int n_in,
                              void* d_out, int out_size, void* d_ws, size_t ws_size,
                              hipStream_t stream) {
  const float* Q = (const float*)d_in[0];
  const float* K = (const float*)d_in[1];
  const float* V = (const float*)d_in[2];
  const int* mask = (const int*)d_in[3];
  float* outO = (float*)d_out;
  float* outP = outO + (size_t)B_ * H_ * S_ * D_;

  const size_t elems = (size_t)B_ * H_ * S_ * D_;     // 4,194,304 per tensor
  if (ws_size >= elems * 2 * 3) {
    ushort* Qw = (ushort*)d_ws;
    ushort* Kw = Qw + elems;
    ushort* Vw = Kw + elems;
    conv_kernel<<<dim3(NKT, BH_, 3), dim3(256), 0, stream>>>(Q, K, V, Qw, Kw, Vw);
    attn2_kernel<<<dim3(S_/64, BH_), dim3(256), 0, stream>>>(Qw, Kw, Vw, mask, outO, outP);
  } else {
    attn_kernel<<<dim3(S_/64, BH_), dim3(256), 0, stream>>>(Q, K, V, mask, outO, outP);
  }
}